// Round 1
// baseline (256.016 us; speedup 1.0000x reference)
//
#include <hip/hip_runtime.h>
#include <hip/hip_bf16.h>

#define B_N 256
#define L_Q 64
#define FEAT_N 2048
#define UNITS_N 512
#define EMB_N 256
#define VOCAB_N 32000

typedef __attribute__((ext_vector_type(8))) short bf16x8;
typedef __attribute__((ext_vector_type(4))) float f32x4;

__device__ __forceinline__ unsigned short f2bf(float x) {
  union { float f; unsigned int u; } c; c.f = x;
  unsigned int u = c.u + 0x7FFFu + ((c.u >> 16) & 1u);
  return (unsigned short)(u >> 16);
}

__device__ __forceinline__ float sigmoidf_(float x) { return 1.0f / (1.0f + __expf(-x)); }

// A-fragment layout for mfma_f32_16x16x32_bf16:
//   frag element (row, k):  rt=row>>4, lr=row&15, ks=k>>5, lq=(k>>3)&3, j=k&7
//   ushort index = ((rt*KS + ks)*64 + (lq*16+lr))*8 + j     (KS = K/32)
__device__ __forceinline__ void store_frag4(unsigned short* base, int KS, int row, int k0,
                                            float a, float b, float c, float d) {
  int rt = row >> 4, lr = row & 15;
  int ks = k0 >> 5, lq = (k0 >> 3) & 3, j0 = k0 & 7;
  union { unsigned long long u; unsigned short s[4]; } p;
  p.s[0] = f2bf(a); p.s[1] = f2bf(b); p.s[2] = f2bf(c); p.s[3] = f2bf(d);
  *reinterpret_cast<unsigned long long*>(base + (((rt * KS + ks) * 64) + (lq * 16 + lr)) * 8 + j0) = p.u;
}

// ---- W1 (2048x512 f32) -> lane-fragment bf16 layout:
// ushort offset = ((kt*32 + c)*64 + l)*8 + j ; n = c*16+(l&15), k = kt*32+(l>>4)*8+j
__global__ void k_w1s(const float* __restrict__ W1, unsigned short* __restrict__ W1s) {
  int t = blockIdx.x * 256 + threadIdx.x;      // 0..131071, one 16B frag each
  int l = t & 63;
  int c = (t >> 6) & 31;
  int kt = t >> 11;
  int n = c * 16 + (l & 15);
  int k0 = kt * 32 + (l >> 4) * 8;
  union { bf16x8 v; unsigned short s[8]; } fr;
#pragma unroll
  for (int j = 0; j < 8; ++j) fr.s[j] = f2bf(W1[(size_t)(k0 + j) * UNITS_N + n]);
  *reinterpret_cast<bf16x8*>(W1s + (size_t)t * 8) = fr.v;
}

// ---- hidden -> A-frags (KS=16) ; emb gather -> xin-frags (KS=24, k base 512)
__global__ void k_prep(const float* __restrict__ hidden,
                       const float* __restrict__ emb_table,
                       const int* __restrict__ tok,
                       unsigned short* __restrict__ hfrag,
                       unsigned short* __restrict__ xinfrag) {
  int t = blockIdx.x * 256 + threadIdx.x;
  if (t < 32768) {
    int b = t >> 7, k0 = (t & 127) * 4;
    const float* s = hidden + (size_t)b * UNITS_N + k0;
    store_frag4(hfrag, 16, b, k0, s[0], s[1], s[2], s[3]);
  } else if (t < 49152) {
    int t2 = t - 32768;
    int b = t2 >> 6, e0 = (t2 & 63) * 4;
    const float* s = emb_table + (size_t)tok[b] * EMB_N + e0;
    store_frag4(xinfrag, 24, b, 512 + e0, s[0], s[1], s[2], s[3]);
  }
}

// ---- generic small MFMA GEMM: out[M=256][N] = A(256xK, frag bf16) @ W(KxN f32) + bias
// grid (N/64, 4), 256 thr (4 waves). Wave w -> row-tile rt = by*4+w, 64 cols.
// MODE 0: f32 row-major out.  MODE 1: bf16 A-frag out (k_out = col, KSo chunks).
template <int MODE>
__launch_bounds__(256)
__global__ void k_small(const unsigned short* __restrict__ Afrag, int KS,
                        const float* __restrict__ W, int N,
                        const float* __restrict__ bias,
                        float* __restrict__ outF,
                        unsigned short* __restrict__ outFrag, int KSo) {
  __shared__ unsigned short Bb[4 * 64 * 8];   // [c][l][8]
  int t = threadIdx.x;
  int w = t >> 6, l = t & 63;
  int n0 = blockIdx.x * 64;
  int rt = blockIdx.y * 4 + w;

  f32x4 acc[4];
#pragma unroll
  for (int c = 0; c < 4; ++c) acc[c] = (f32x4){0.f, 0.f, 0.f, 0.f};

  int sn = t & 63, kc = t >> 6;
  unsigned short* wdst = &Bb[(((sn >> 4) * 64) + ((sn & 15) | (kc << 4))) * 8];
  const float* Wp = W + n0 + sn;

  float wreg[8];
#pragma unroll
  for (int j = 0; j < 8; ++j) wreg[j] = Wp[(size_t)(kc * 8 + j) * N];

  for (int kt = 0; kt < KS; ++kt) {
    __syncthreads();
    {
      union { bf16x8 v; unsigned short s[8]; } p;
#pragma unroll
      for (int j = 0; j < 8; ++j) p.s[j] = f2bf(wreg[j]);
      *reinterpret_cast<bf16x8*>(wdst) = p.v;
    }
    __syncthreads();
    if (kt + 1 < KS) {
#pragma unroll
      for (int j = 0; j < 8; ++j) wreg[j] = Wp[(size_t)((kt + 1) * 32 + kc * 8 + j) * N];
    }
    bf16x8 af = *reinterpret_cast<const bf16x8*>(Afrag + ((size_t)(rt * KS + kt) * 64 + l) * 8);
#pragma unroll
    for (int c = 0; c < 4; ++c) {
      bf16x8 bf = *reinterpret_cast<const bf16x8*>(&Bb[((c * 64) + l) * 8]);
      acc[c] = __builtin_amdgcn_mfma_f32_16x16x32_bf16(af, bf, acc[c], 0, 0, 0);
    }
  }

#pragma unroll
  for (int c = 0; c < 4; ++c) {
    int col = n0 + c * 16 + (l & 15);
    float bv = bias[col];
#pragma unroll
    for (int i = 0; i < 4; ++i) {
      int row = rt * 16 + ((l >> 4) * 4) + i;
      float v = acc[c][i] + bv;
      if (MODE == 0) {
        outF[(size_t)row * N + col] = v;
      } else {
        int k = col;
        outFrag[(((size_t)(row >> 4) * KSo + (k >> 5)) * 64 + (((k >> 3) & 3) * 16 + (row & 15))) * 8 + (k & 7)] = f2bf(v);
      }
    }
  }
}

// ---- GEMM1 + tanh + @V + softmax: one block per batch row b.
// BM=64 (=L), BN=512, BK=32, 256 thr = 4 waves; wave w: 4 row-tiles x cols [w*128, w*128+128)
__launch_bounds__(256, 1)
__global__ void k_gemm1(const float* __restrict__ features,
                        const unsigned short* __restrict__ W1s,
                        const float* __restrict__ hproj,
                        const float* __restrict__ b1,
                        const float* __restrict__ V,
                        float* __restrict__ attn) {
  __shared__ unsigned short Abuf[64 * 40];          // padded rows (40 bf16)
  __shared__ unsigned short Bbuf[32 * 64 * 8];      // [ctile(32)][l][8] = 32 KB
  __shared__ float wlog[4][64];

  int b = blockIdx.x;
  int t = threadIdx.x;
  int w = t >> 6, l = t & 63;

  f32x4 acc[4][8];
#pragma unroll
  for (int rt = 0; rt < 4; ++rt)
#pragma unroll
    for (int ct = 0; ct < 8; ++ct) acc[rt][ct] = (f32x4){0.f, 0.f, 0.f, 0.f};

  const float* Af = features + (size_t)b * 64 * FEAT_N;
  int ar = t >> 2, ak = (t & 3) * 8;

  for (int kt = 0; kt < 64; ++kt) {
    __syncthreads();
    // stage A tile (64x32 f32 -> bf16)
    float4 a0 = *reinterpret_cast<const float4*>(Af + (size_t)ar * FEAT_N + kt * 32 + ak);
    float4 a1 = *reinterpret_cast<const float4*>(Af + (size_t)ar * FEAT_N + kt * 32 + ak + 4);
    union { bf16x8 v; unsigned short s[8]; } ap;
    ap.s[0] = f2bf(a0.x); ap.s[1] = f2bf(a0.y); ap.s[2] = f2bf(a0.z); ap.s[3] = f2bf(a0.w);
    ap.s[4] = f2bf(a1.x); ap.s[5] = f2bf(a1.y); ap.s[6] = f2bf(a1.z); ap.s[7] = f2bf(a1.w);
    *reinterpret_cast<bf16x8*>(&Abuf[ar * 40 + ak]) = ap.v;
    // stage B tile (32KB, already in lane-frag order)
#pragma unroll
    for (int i = 0; i < 8; ++i) {
      int seg = i * 4 + w;
      bf16x8 bv = *reinterpret_cast<const bf16x8*>(W1s + (size_t)kt * 16384 + (size_t)(seg * 64 + l) * 8);
      *reinterpret_cast<bf16x8*>(&Bbuf[(seg * 64 + l) * 8]) = bv;
    }
    __syncthreads();
    bf16x8 afr[4];
#pragma unroll
    for (int rt = 0; rt < 4; ++rt)
      afr[rt] = *reinterpret_cast<const bf16x8*>(&Abuf[(rt * 16 + (l & 15)) * 40 + ((l >> 4) * 8)]);
#pragma unroll
    for (int ct = 0; ct < 8; ++ct) {
      bf16x8 bfr = *reinterpret_cast<const bf16x8*>(&Bbuf[((w * 8 + ct) * 64 + l) * 8]);
#pragma unroll
      for (int rt = 0; rt < 4; ++rt)
        acc[rt][ct] = __builtin_amdgcn_mfma_f32_16x16x32_bf16(afr[rt], bfr, acc[rt][ct], 0, 0, 0);
    }
  }

  // epilogue: logits[row] = sum_col tanh(S + hproj + b1) * V[col]
  float rowpart[16];
#pragma unroll
  for (int r = 0; r < 16; ++r) rowpart[r] = 0.f;
#pragma unroll
  for (int ct = 0; ct < 8; ++ct) {
    int col = w * 128 + ct * 16 + (l & 15);
    float hb = hproj[(size_t)b * UNITS_N + col] + b1[col];
    float vv = V[col];
#pragma unroll
    for (int rt = 0; rt < 4; ++rt)
#pragma unroll
      for (int i = 0; i < 4; ++i)
        rowpart[rt * 4 + i] += tanhf(acc[rt][ct][i] + hb) * vv;
  }
#pragma unroll
  for (int m = 1; m <= 8; m <<= 1)
#pragma unroll
    for (int r = 0; r < 16; ++r) rowpart[r] += __shfl_xor(rowpart[r], m, 64);
  if ((l & 15) == 0) {
    int g = l >> 4;
#pragma unroll
    for (int rt = 0; rt < 4; ++rt)
#pragma unroll
      for (int i = 0; i < 4; ++i)
        wlog[w][rt * 16 + g * 4 + i] = rowpart[rt * 4 + i];
  }
  __syncthreads();
  if (t < 64) {   // wave 0: softmax over the 64 logits (bV cancels)
    float x = wlog[0][t] + wlog[1][t] + wlog[2][t] + wlog[3][t];
    float mx = x;
#pragma unroll
    for (int m = 1; m < 64; m <<= 1) mx = fmaxf(mx, __shfl_xor(mx, m, 64));
    float e = __expf(x - mx);
    float s = e;
#pragma unroll
    for (int m = 1; m < 64; m <<= 1) s += __shfl_xor(s, m, 64);
    attn[(size_t)b * 64 + t] = e / s;
  }
}

// ---- context = sum_l attn*features ; writes tanh(context) and tanh(hidden) as tc-frags (KS=80)
__global__ void k_context(const float* __restrict__ features,
                          const float* __restrict__ attn,
                          const float* __restrict__ hidden,
                          unsigned short* __restrict__ tcfrag) {
  __shared__ float aL[64];
  int b = blockIdx.x, t = threadIdx.x;
  if (t < 64) aL[t] = attn[(size_t)b * 64 + t];
  __syncthreads();
  const float* F = features + (size_t)b * 64 * FEAT_N + t * 4;
  float a0 = 0.f, a1 = 0.f, a2 = 0.f, a3 = 0.f;
#pragma unroll 4
  for (int lr = 0; lr < 64; ++lr) {
    float4 f = *reinterpret_cast<const float4*>(F + (size_t)lr * FEAT_N);
    float av = aL[lr];
    a0 += av * f.x; a1 += av * f.y; a2 += av * f.z; a3 += av * f.w;
  }
  store_frag4(tcfrag, 80, b, t * 4, tanhf(a0), tanhf(a1), tanhf(a2), tanhf(a3));
  if (t < 128) {
    const float* H = hidden + (size_t)b * UNITS_N + t * 4;
    store_frag4(tcfrag, 80, b, 2048 + t * 4, tanhf(H[0]), tanhf(H[1]), tanhf(H[2]), tanhf(H[3]));
  }
}

// ---- GRU activation (h_prev = 0): h = (1-sigmoid(z)) * tanh(hh)
__global__ void k_gru_act(const float* __restrict__ gx, float* __restrict__ hout,
                          unsigned short* __restrict__ hfrag) {
  int t = blockIdx.x * 256 + threadIdx.x;       // 32768
  int b = t >> 7, n0 = (t & 127) * 4;
  const float* g = gx + (size_t)b * 1536;
  float4 z4 = *reinterpret_cast<const float4*>(g + n0);
  float4 h4 = *reinterpret_cast<const float4*>(g + 1024 + n0);
  float r0 = (1.f - sigmoidf_(z4.x)) * tanhf(h4.x);
  float r1 = (1.f - sigmoidf_(z4.y)) * tanhf(h4.y);
  float r2 = (1.f - sigmoidf_(z4.z)) * tanhf(h4.z);
  float r3 = (1.f - sigmoidf_(z4.w)) * tanhf(h4.w);
  float4 o; o.x = r0; o.y = r1; o.z = r2; o.w = r3;
  *reinterpret_cast<float4*>(hout + (size_t)b * UNITS_N + n0) = o;
  store_frag4(hfrag, 16, b, n0, r0, r1, r2, r3);
}

// ---- fc2: out(256x32000) = x1(256x512 frags) @ fc2_W + fc2_b. grid 500, M full per block.
__launch_bounds__(256)
__global__ void k_fc2(const unsigned short* __restrict__ x1frag,
                      const float* __restrict__ W, const float* __restrict__ bias,
                      float* __restrict__ out) {
  __shared__ unsigned short Bb[4 * 64 * 8];
  int t = threadIdx.x, w = t >> 6, l = t & 63;
  int n0 = blockIdx.x * 64;
  f32x4 acc[4][4];
#pragma unroll
  for (int r = 0; r < 4; ++r)
#pragma unroll
    for (int c = 0; c < 4; ++c) acc[r][c] = (f32x4){0.f, 0.f, 0.f, 0.f};

  int sn = t & 63, kc = t >> 6;
  unsigned short* wdst = &Bb[(((sn >> 4) * 64) + ((sn & 15) | (kc << 4))) * 8];
  const float* Wp = W + n0 + sn;
  float wreg[8];
#pragma unroll
  for (int j = 0; j < 8; ++j) wreg[j] = Wp[(size_t)(kc * 8 + j) * VOCAB_N];

  for (int kt = 0; kt < 16; ++kt) {
    __syncthreads();
    {
      union { bf16x8 v; unsigned short s[8]; } p;
#pragma unroll
      for (int j = 0; j < 8; ++j) p.s[j] = f2bf(wreg[j]);
      *reinterpret_cast<bf16x8*>(wdst) = p.v;
    }
    __syncthreads();
    if (kt < 15) {
#pragma unroll
      for (int j = 0; j < 8; ++j) wreg[j] = Wp[(size_t)((kt + 1) * 32 + kc * 8 + j) * VOCAB_N];
    }
    bf16x8 bf[4];
#pragma unroll
    for (int c = 0; c < 4; ++c) bf[c] = *reinterpret_cast<const bf16x8*>(&Bb[((c * 64) + l) * 8]);
#pragma unroll
    for (int rti = 0; rti < 4; ++rti) {
      bf16x8 af = *reinterpret_cast<const bf16x8*>(x1frag + ((size_t)((w * 4 + rti) * 16 + kt) * 64 + l) * 8);
#pragma unroll
      for (int c = 0; c < 4; ++c)
        acc[rti][c] = __builtin_amdgcn_mfma_f32_16x16x32_bf16(af, bf[c], acc[rti][c], 0, 0, 0);
    }
  }
#pragma unroll
  for (int c = 0; c < 4; ++c) {
    int col = n0 + c * 16 + (l & 15);
    float bv = bias[col];
#pragma unroll
    for (int rti = 0; rti < 4; ++rti)
#pragma unroll
      for (int i = 0; i < 4; ++i) {
        int row = w * 64 + rti * 16 + (l >> 4) * 4 + i;
        out[(size_t)row * VOCAB_N + col] = acc[rti][c][i] + bv;
      }
  }
}

extern "C" void kernel_launch(void* const* d_in, const int* in_sizes, int n_in,
                              void* d_out, int out_size, void* d_ws, size_t ws_size,
                              hipStream_t stream) {
  const int*   tok        = (const int*)d_in[0];
  const float* features   = (const float*)d_in[1];
  const float* hidden     = (const float*)d_in[2];
  const float* W1         = (const float*)d_in[3];
  const float* b1         = (const float*)d_in[4];
  const float* W2         = (const float*)d_in[5];
  const float* b2         = (const float*)d_in[6];
  const float* V          = (const float*)d_in[7];
  // d_in[8] = bV: cancels in softmax; raw logits are not an output
  const float* W3         = (const float*)d_in[9];
  const float* b3         = (const float*)d_in[10];
  const float* emb_table  = (const float*)d_in[11];
  const float* gru_kernel = (const float*)d_in[12];
  // d_in[13] = gru_rec: unused because h0 == 0
  const float* gru_bias   = (const float*)d_in[14];
  const float* fc1_W      = (const float*)d_in[15];
  const float* fc1_b      = (const float*)d_in[16];
  const float* fc2_W      = (const float*)d_in[17];
  const float* fc2_b      = (const float*)d_in[18];

  float* out_logits = (float*)d_out;
  float* out_h      = out_logits + (size_t)B_N * VOCAB_N;   // +8,192,000
  float* out_attn   = out_h + (size_t)B_N * UNITS_N;        // +131,072

  char* ws = (char*)d_ws;
  unsigned short* W1s     = (unsigned short*)(ws);              // 2,097,152 B
  float*          hproj   = (float*)(ws + 2097152);             //   524,288 B
  unsigned short* hfrag   = (unsigned short*)(ws + 2621440);    //   262,144 B
  unsigned short* tcfrag  = (unsigned short*)(ws + 2883584);    // 1,310,720 B
  unsigned short* xinfrag = (unsigned short*)(ws + 4194304);    //   393,216 B
  float*          gx      = (float*)(ws + 4587520);             // 1,572,864 B
  unsigned short* hnfrag  = (unsigned short*)(ws + 6160384);    //   262,144 B
  unsigned short* x1frag  = (unsigned short*)(ws + 6422528);    //   262,144 B

  k_w1s<<<dim3(512), dim3(256), 0, stream>>>(W1, W1s);
  k_prep<<<dim3(192), dim3(256), 0, stream>>>(hidden, emb_table, tok, hfrag, xinfrag);
  // hproj = hidden @ W2 + b2
  k_small<0><<<dim3(8, 4), dim3(256), 0, stream>>>(hfrag, 16, W2, 512, b2, hproj, (unsigned short*)nullptr, 0);
  // score/logits/attn
  k_gemm1<<<dim3(256), dim3(256), 0, stream>>>(features, W1s, hproj, b1, V, out_attn);
  // context + tanh-concat frags
  k_context<<<dim3(256), dim3(512), 0, stream>>>(features, out_attn, hidden, tcfrag);
  // cvh = tc @ W3 + b3 -> xin frags (k 0..511)
  k_small<1><<<dim3(8, 4), dim3(256), 0, stream>>>(tcfrag, 80, W3, 512, b3, (float*)nullptr, xinfrag, 24);
  // gx = x_in @ gru_kernel + gru_bias
  k_small<0><<<dim3(24, 4), dim3(256), 0, stream>>>(xinfrag, 24, gru_kernel, 1536, gru_bias, gx, (unsigned short*)nullptr, 0);
  // h_new
  k_gru_act<<<dim3(128), dim3(256), 0, stream>>>(gx, out_h, hnfrag);
  // x1 = h_new @ fc1_W + fc1_b -> frags
  k_small<1><<<dim3(8, 4), dim3(256), 0, stream>>>(hnfrag, 16, fc1_W, 512, fc1_b, (float*)nullptr, x1frag, 16);
  // logits_out = x1 @ fc2_W + fc2_b
  k_fc2<<<dim3(500), dim3(256), 0, stream>>>(x1frag, fc2_W, fc2_b, out_logits);
}

// Round 2
// 224.594 us; speedup vs baseline: 1.1399x; 1.1399x over previous
//
#include <hip/hip_runtime.h>
#include <hip/hip_bf16.h>

#define B_N 256
#define L_Q 64
#define FEAT_N 2048
#define UNITS_N 512
#define EMB_N 256
#define VOCAB_N 32000

typedef __attribute__((ext_vector_type(8))) short bf16x8;
typedef __attribute__((ext_vector_type(4))) float f32x4;

__device__ __forceinline__ unsigned short f2bf(float x) {
  union { float f; unsigned int u; } c; c.f = x;
  unsigned int u = c.u + 0x7FFFu + ((c.u >> 16) & 1u);
  return (unsigned short)(u >> 16);
}

__device__ __forceinline__ float sigmoidf_(float x) { return 1.0f / (1.0f + __expf(-x)); }

// A-fragment layout for mfma_f32_16x16x32_bf16:
//   ushort index = ((rt*KS + ks)*64 + (lq*16+lr))*8 + j   (KS = K/32)
//   row = rt*16+lr, k = ks*32 + lq*8 + j
__device__ __forceinline__ void store_frag4(unsigned short* base, int KS, int row, int k0,
                                            float a, float b, float c, float d) {
  int rt = row >> 4, lr = row & 15;
  int ks = k0 >> 5, lq = (k0 >> 3) & 3, j0 = k0 & 7;
  union { unsigned long long u; unsigned short s[4]; } p;
  p.s[0] = f2bf(a); p.s[1] = f2bf(b); p.s[2] = f2bf(c); p.s[3] = f2bf(d);
  *reinterpret_cast<unsigned long long*>(base + (((rt * KS + ks) * 64) + (lq * 16 + lr)) * 8 + j0) = p.u;
}

__device__ __forceinline__ void gload_lds16(const void* g, void* lds) {
  __builtin_amdgcn_global_load_lds(
      (const __attribute__((address_space(1))) unsigned int*)(uintptr_t)g,
      (__attribute__((address_space(3))) unsigned int*)(unsigned)(uintptr_t)lds,
      16, 0, 0);
}

// ---- fused prep: W1 -> frag bf16 (blocks 0..511); hidden/emb -> frags (blocks 512..703)
__global__ void k_prep_all(const float* __restrict__ W1, unsigned short* __restrict__ W1s,
                           const float* __restrict__ hidden,
                           const float* __restrict__ emb_table,
                           const int* __restrict__ tok,
                           unsigned short* __restrict__ hfrag,
                           unsigned short* __restrict__ xinfrag) {
  int bb = blockIdx.x;
  if (bb < 512) {
    int t = bb * 256 + threadIdx.x;            // one 16B frag each
    int l = t & 63;
    int c = (t >> 6) & 31;
    int kt = t >> 11;
    int n = c * 16 + (l & 15);
    int k0 = kt * 32 + (l >> 4) * 8;
    union { bf16x8 v; unsigned short s[8]; } fr;
#pragma unroll
    for (int j = 0; j < 8; ++j) fr.s[j] = f2bf(W1[(size_t)(k0 + j) * UNITS_N + n]);
    *reinterpret_cast<bf16x8*>(W1s + (size_t)t * 8) = fr.v;
  } else {
    int t = (bb - 512) * 256 + threadIdx.x;
    if (t < 32768) {
      int b = t >> 7, k0 = (t & 127) * 4;
      const float* s = hidden + (size_t)b * UNITS_N + k0;
      store_frag4(hfrag, 16, b, k0, s[0], s[1], s[2], s[3]);
    } else if (t < 49152) {
      int t2 = t - 32768;
      int b = t2 >> 6, e0 = (t2 & 63) * 4;
      const float* s = emb_table + (size_t)tok[b] * EMB_N + e0;
      store_frag4(xinfrag, 24, b, 512 + e0, s[0], s[1], s[2], s[3]);
    }
  }
}

// ---- generic small MFMA GEMM (unchanged from round 1)
template <int MODE>
__launch_bounds__(256)
__global__ void k_small(const unsigned short* __restrict__ Afrag, int KS,
                        const float* __restrict__ W, int N,
                        const float* __restrict__ bias,
                        float* __restrict__ outF,
                        unsigned short* __restrict__ outFrag, int KSo) {
  __shared__ unsigned short Bb[4 * 64 * 8];
  int t = threadIdx.x;
  int w = t >> 6, l = t & 63;
  int n0 = blockIdx.x * 64;
  int rt = blockIdx.y * 4 + w;

  f32x4 acc[4];
#pragma unroll
  for (int c = 0; c < 4; ++c) acc[c] = (f32x4){0.f, 0.f, 0.f, 0.f};

  int sn = t & 63, kc = t >> 6;
  unsigned short* wdst = &Bb[(((sn >> 4) * 64) + ((sn & 15) | (kc << 4))) * 8];
  const float* Wp = W + n0 + sn;

  float wreg[8];
#pragma unroll
  for (int j = 0; j < 8; ++j) wreg[j] = Wp[(size_t)(kc * 8 + j) * N];

  for (int kt = 0; kt < KS; ++kt) {
    __syncthreads();
    {
      union { bf16x8 v; unsigned short s[8]; } p;
#pragma unroll
      for (int j = 0; j < 8; ++j) p.s[j] = f2bf(wreg[j]);
      *reinterpret_cast<bf16x8*>(wdst) = p.v;
    }
    __syncthreads();
    if (kt + 1 < KS) {
#pragma unroll
      for (int j = 0; j < 8; ++j) wreg[j] = Wp[(size_t)((kt + 1) * 32 + kc * 8 + j) * N];
    }
    bf16x8 af = *reinterpret_cast<const bf16x8*>(Afrag + ((size_t)(rt * KS + kt) * 64 + l) * 8);
#pragma unroll
    for (int c = 0; c < 4; ++c) {
      bf16x8 bf = *reinterpret_cast<const bf16x8*>(&Bb[((c * 64) + l) * 8]);
      acc[c] = __builtin_amdgcn_mfma_f32_16x16x32_bf16(af, bf, acc[c], 0, 0, 0);
    }
  }

#pragma unroll
  for (int c = 0; c < 4; ++c) {
    int col = n0 + c * 16 + (l & 15);
    float bv = bias[col];
#pragma unroll
    for (int i = 0; i < 4; ++i) {
      int row = rt * 16 + ((l >> 4) * 4) + i;
      float v = acc[c][i] + bv;
      if (MODE == 0) {
        outF[(size_t)row * N + col] = v;
      } else {
        int k = col;
        outFrag[(((size_t)(row >> 4) * KSo + (k >> 5)) * 64 + (((k >> 3) & 3) * 16 + (row & 15))) * 8 + (k & 7)] = f2bf(v);
      }
    }
  }
}

// ---- GEMM1 partial: M=16384, N=512 (2 halves), K=2048. BM=64, BN=256, BK=64.
// 512 blocks, 4 waves; wave w covers cols [w*64,(w+1)*64) of the half.
// Epilogue: partial logit = sum_cols tanh(S + hproj + b1)*V -> partials[h][16384]
__launch_bounds__(256, 2)
__global__ void k_gemm1p(const float* __restrict__ features,
                         const unsigned short* __restrict__ W1s,
                         const float* __restrict__ hproj,
                         const float* __restrict__ b1,
                         const float* __restrict__ V,
                         float* __restrict__ partials) {
  __shared__ unsigned short Bb[2 * 16 * 64 * 8];   // 32 KB [ksub][slot][lane][8]
  __shared__ unsigned short Ab[2 * 4 * 64 * 8];    //  8 KB [ks][rt][lane][8]
  __shared__ float wlog[4][64];

  int t = threadIdx.x, w = t >> 6, l = t & 63;
  int bid = blockIdx.x;
  int swz = (bid & 7) * 64 + (bid >> 3);   // bijective, 512 = 8*64
  int h = swz & 1;                          // N half
  int mb = swz >> 1;                        // batch row block (== batch index)

  f32x4 acc[4][4];
#pragma unroll
  for (int rt = 0; rt < 4; ++rt)
#pragma unroll
    for (int ct = 0; ct < 4; ++ct) acc[rt][ct] = (f32x4){0.f, 0.f, 0.f, 0.f};

  // A staging: thread -> row r, k-quad q (16 consecutive floats)
  int r = t >> 2, q = t & 3;
  const float* Ap = features + (size_t)(mb * 64 + r) * FEAT_N + q * 16;
  int rt_ = r >> 4, lr_ = r & 15, ks_ = q >> 1, lq0 = (q & 1) * 2;
  unsigned short* aw0 = &Ab[((((ks_ * 4 + rt_) * 4) + lq0) * 16 + lr_) * 8];
  unsigned short* aw1 = aw0 + 128;   // lq0+1

  const char* W1c = (const char*)W1s;
  float4 ar[4];
  {
    const float* p = Ap;
    ar[0] = *reinterpret_cast<const float4*>(p);
    ar[1] = *reinterpret_cast<const float4*>(p + 4);
    ar[2] = *reinterpret_cast<const float4*>(p + 8);
    ar[3] = *reinterpret_cast<const float4*>(p + 12);
  }

  for (int kt = 0; kt < 32; ++kt) {
    __syncthreads();
    // B: 32 chunks of 1KB via global_load_lds (8 per wave)
#pragma unroll
    for (int i = 0; i < 8; ++i) {
      int c = w * 8 + i, ksub = c >> 4, s = c & 15;
      size_t gb = ((size_t)((kt * 2 + ksub) * 32 + h * 16 + s) << 10) + (size_t)l * 16;
      gload_lds16(W1c + gb, (char*)Bb + ((ksub * 16 + s) << 10));
    }
    // A: convert regs -> frags
    {
      union { bf16x8 v; unsigned short s_[8]; } p0, p1;
      p0.s_[0] = f2bf(ar[0].x); p0.s_[1] = f2bf(ar[0].y); p0.s_[2] = f2bf(ar[0].z); p0.s_[3] = f2bf(ar[0].w);
      p0.s_[4] = f2bf(ar[1].x); p0.s_[5] = f2bf(ar[1].y); p0.s_[6] = f2bf(ar[1].z); p0.s_[7] = f2bf(ar[1].w);
      p1.s_[0] = f2bf(ar[2].x); p1.s_[1] = f2bf(ar[2].y); p1.s_[2] = f2bf(ar[2].z); p1.s_[3] = f2bf(ar[2].w);
      p1.s_[4] = f2bf(ar[3].x); p1.s_[5] = f2bf(ar[3].y); p1.s_[6] = f2bf(ar[3].z); p1.s_[7] = f2bf(ar[3].w);
      *reinterpret_cast<bf16x8*>(aw0) = p0.v;
      *reinterpret_cast<bf16x8*>(aw1) = p1.v;
    }
    if (kt + 1 < 32) {
      const float* p = Ap + (kt + 1) * 64;
      ar[0] = *reinterpret_cast<const float4*>(p);
      ar[1] = *reinterpret_cast<const float4*>(p + 4);
      ar[2] = *reinterpret_cast<const float4*>(p + 8);
      ar[3] = *reinterpret_cast<const float4*>(p + 12);
    }
    __syncthreads();
    // compute: 32 MFMAs
#pragma unroll
    for (int ks = 0; ks < 2; ++ks) {
      bf16x8 bfr[4];
#pragma unroll
      for (int ct = 0; ct < 4; ++ct)
        bfr[ct] = *reinterpret_cast<const bf16x8*>(&Bb[((ks * 16 + w * 4 + ct) * 64 + l) * 8]);
#pragma unroll
      for (int rt = 0; rt < 4; ++rt) {
        bf16x8 af = *reinterpret_cast<const bf16x8*>(&Ab[((ks * 4 + rt) * 64 + l) * 8]);
#pragma unroll
        for (int ct = 0; ct < 4; ++ct)
          acc[rt][ct] = __builtin_amdgcn_mfma_f32_16x16x32_bf16(af, bfr[ct], acc[rt][ct], 0, 0, 0);
      }
    }
  }

  // epilogue: partial logits over this half's 256 cols
  float rowpart[16];
#pragma unroll
  for (int i = 0; i < 16; ++i) rowpart[i] = 0.f;
#pragma unroll
  for (int ct = 0; ct < 4; ++ct) {
    int col = h * 256 + w * 64 + ct * 16 + (l & 15);
    float hb = hproj[(size_t)mb * UNITS_N + col] + b1[col];
    float vv = V[col];
#pragma unroll
    for (int rt = 0; rt < 4; ++rt)
#pragma unroll
      for (int i = 0; i < 4; ++i)
        rowpart[rt * 4 + i] += tanhf(acc[rt][ct][i] + hb) * vv;
  }
#pragma unroll
  for (int m = 1; m <= 8; m <<= 1)
#pragma unroll
    for (int i = 0; i < 16; ++i) rowpart[i] += __shfl_xor(rowpart[i], m, 64);
  if ((l & 15) == 0) {
    int g = l >> 4;
#pragma unroll
    for (int rt = 0; rt < 4; ++rt)
#pragma unroll
      for (int i = 0; i < 4; ++i)
        wlog[w][rt * 16 + g * 4 + i] = rowpart[rt * 4 + i];
  }
  __syncthreads();
  if (t < 64) {
    float x = wlog[0][t] + wlog[1][t] + wlog[2][t] + wlog[3][t];
    partials[h * 16384 + mb * 64 + t] = x;
  }
}

// ---- softmax (from 2 partials) + context + tanh-concat frags
__global__ void k_context(const float* __restrict__ features,
                          const float* __restrict__ partials,
                          const float* __restrict__ hidden,
                          unsigned short* __restrict__ tcfrag,
                          float* __restrict__ attn_out) {
  __shared__ float aL[64];
  int b = blockIdx.x, t = threadIdx.x;
  if (t < 64) {
    float x = partials[b * 64 + t] + partials[16384 + b * 64 + t];
    float mx = x;
#pragma unroll
    for (int m = 1; m < 64; m <<= 1) mx = fmaxf(mx, __shfl_xor(mx, m, 64));
    float e = __expf(x - mx);
    float s = e;
#pragma unroll
    for (int m = 1; m < 64; m <<= 1) s += __shfl_xor(s, m, 64);
    float a = e / s;
    aL[t] = a;
    attn_out[(size_t)b * 64 + t] = a;
  }
  __syncthreads();
  const float* F = features + (size_t)b * 64 * FEAT_N + t * 4;
  float a0 = 0.f, a1 = 0.f, a2 = 0.f, a3 = 0.f;
#pragma unroll 4
  for (int lr = 0; lr < 64; ++lr) {
    float4 f = *reinterpret_cast<const float4*>(F + (size_t)lr * FEAT_N);
    float av = aL[lr];
    a0 += av * f.x; a1 += av * f.y; a2 += av * f.z; a3 += av * f.w;
  }
  store_frag4(tcfrag, 80, b, t * 4, tanhf(a0), tanhf(a1), tanhf(a2), tanhf(a3));
  if (t < 128) {
    const float* H = hidden + (size_t)b * UNITS_N + t * 4;
    store_frag4(tcfrag, 80, b, 2048 + t * 4, tanhf(H[0]), tanhf(H[1]), tanhf(H[2]), tanhf(H[3]));
  }
}

// ---- GRU activation (h_prev = 0): h = (1-sigmoid(z)) * tanh(hh)
__global__ void k_gru_act(const float* __restrict__ gx, float* __restrict__ hout,
                          unsigned short* __restrict__ hfrag) {
  int t = blockIdx.x * 256 + threadIdx.x;       // 32768
  int b = t >> 7, n0 = (t & 127) * 4;
  const float* g = gx + (size_t)b * 1536;
  float4 z4 = *reinterpret_cast<const float4*>(g + n0);
  float4 h4 = *reinterpret_cast<const float4*>(g + 1024 + n0);
  float r0 = (1.f - sigmoidf_(z4.x)) * tanhf(h4.x);
  float r1 = (1.f - sigmoidf_(z4.y)) * tanhf(h4.y);
  float r2 = (1.f - sigmoidf_(z4.z)) * tanhf(h4.z);
  float r3 = (1.f - sigmoidf_(z4.w)) * tanhf(h4.w);
  float4 o; o.x = r0; o.y = r1; o.z = r2; o.w = r3;
  *reinterpret_cast<float4*>(hout + (size_t)b * UNITS_N + n0) = o;
  store_frag4(hfrag, 16, b, n0, r0, r1, r2, r3);
}

// ---- fc2: out(256x32000) = x1 @ fc2_W + fc2_b
__launch_bounds__(256)
__global__ void k_fc2(const unsigned short* __restrict__ x1frag,
                      const float* __restrict__ W, const float* __restrict__ bias,
                      float* __restrict__ out) {
  __shared__ unsigned short Bb[4 * 64 * 8];
  int t = threadIdx.x, w = t >> 6, l = t & 63;
  int n0 = blockIdx.x * 64;
  f32x4 acc[4][4];
#pragma unroll
  for (int r = 0; r < 4; ++r)
#pragma unroll
    for (int c = 0; c < 4; ++c) acc[r][c] = (f32x4){0.f, 0.f, 0.f, 0.f};

  int sn = t & 63, kc = t >> 6;
  unsigned short* wdst = &Bb[(((sn >> 4) * 64) + ((sn & 15) | (kc << 4))) * 8];
  const float* Wp = W + n0 + sn;
  float wreg[8];
#pragma unroll
  for (int j = 0; j < 8; ++j) wreg[j] = Wp[(size_t)(kc * 8 + j) * VOCAB_N];

  for (int kt = 0; kt < 16; ++kt) {
    __syncthreads();
    {
      union { bf16x8 v; unsigned short s[8]; } p;
#pragma unroll
      for (int j = 0; j < 8; ++j) p.s[j] = f2bf(wreg[j]);
      *reinterpret_cast<bf16x8*>(wdst) = p.v;
    }
    __syncthreads();
    if (kt < 15) {
#pragma unroll
      for (int j = 0; j < 8; ++j) wreg[j] = Wp[(size_t)((kt + 1) * 32 + kc * 8 + j) * VOCAB_N];
    }
    bf16x8 bf[4];
#pragma unroll
    for (int c = 0; c < 4; ++c) bf[c] = *reinterpret_cast<const bf16x8*>(&Bb[((c * 64) + l) * 8]);
#pragma unroll
    for (int rti = 0; rti < 4; ++rti) {
      bf16x8 af = *reinterpret_cast<const bf16x8*>(x1frag + ((size_t)((w * 4 + rti) * 16 + kt) * 64 + l) * 8);
#pragma unroll
      for (int c = 0; c < 4; ++c)
        acc[rti][c] = __builtin_amdgcn_mfma_f32_16x16x32_bf16(af, bf[c], acc[rti][c], 0, 0, 0);
    }
  }
#pragma unroll
  for (int c = 0; c < 4; ++c) {
    int col = n0 + c * 16 + (l & 15);
    float bv = bias[col];
#pragma unroll
    for (int rti = 0; rti < 4; ++rti)
#pragma unroll
      for (int i = 0; i < 4; ++i) {
        int row = w * 64 + rti * 16 + (l >> 4) * 4 + i;
        out[(size_t)row * VOCAB_N + col] = acc[rti][c][i] + bv;
      }
  }
}

extern "C" void kernel_launch(void* const* d_in, const int* in_sizes, int n_in,
                              void* d_out, int out_size, void* d_ws, size_t ws_size,
                              hipStream_t stream) {
  const int*   tok        = (const int*)d_in[0];
  const float* features   = (const float*)d_in[1];
  const float* hidden     = (const float*)d_in[2];
  const float* W1         = (const float*)d_in[3];
  const float* b1         = (const float*)d_in[4];
  const float* W2         = (const float*)d_in[5];
  const float* b2         = (const float*)d_in[6];
  const float* V          = (const float*)d_in[7];
  // d_in[8] = bV: cancels in softmax
  const float* W3         = (const float*)d_in[9];
  const float* b3         = (const float*)d_in[10];
  const float* emb_table  = (const float*)d_in[11];
  const float* gru_kernel = (const float*)d_in[12];
  // d_in[13] = gru_rec: unused (h0 == 0)
  const float* gru_bias   = (const float*)d_in[14];
  const float* fc1_W      = (const float*)d_in[15];
  const float* fc1_b      = (const float*)d_in[16];
  const float* fc2_W      = (const float*)d_in[17];
  const float* fc2_b      = (const float*)d_in[18];

  float* out_logits = (float*)d_out;
  float* out_h      = out_logits + (size_t)B_N * VOCAB_N;
  float* out_attn   = out_h + (size_t)B_N * UNITS_N;

  char* ws = (char*)d_ws;
  unsigned short* W1s     = (unsigned short*)(ws);              // 2,097,152 B
  float*          hproj   = (float*)(ws + 2097152);             //   524,288 B
  unsigned short* hfrag   = (unsigned short*)(ws + 2621440);    //   262,144 B
  unsigned short* tcfrag  = (unsigned short*)(ws + 2883584);    // 1,310,720 B
  unsigned short* xinfrag = (unsigned short*)(ws + 4194304);    //   393,216 B
  float*          gx      = (float*)(ws + 4587520);             // 1,572,864 B
  unsigned short* hnfrag  = (unsigned short*)(ws + 6160384);    //   262,144 B
  unsigned short* x1frag  = (unsigned short*)(ws + 6422528);    //   262,144 B
  float*          partials= (float*)(ws + 6684672);             //   131,072 B

  k_prep_all<<<dim3(704), dim3(256), 0, stream>>>(W1, W1s, hidden, emb_table, tok, hfrag, xinfrag);
  // hproj = hidden @ W2 + b2
  k_small<0><<<dim3(8, 4), dim3(256), 0, stream>>>(hfrag, 16, W2, 512, b2, hproj, (unsigned short*)nullptr, 0);
  // partial logits
  k_gemm1p<<<dim3(512), dim3(256), 0, stream>>>(features, W1s, hproj, b1, V, partials);
  // softmax + context + tanh-concat frags (writes attn output)
  k_context<<<dim3(256), dim3(512), 0, stream>>>(features, partials, hidden, tcfrag, out_attn);
  // cvh = tc @ W3 + b3 -> xin frags
  k_small<1><<<dim3(8, 4), dim3(256), 0, stream>>>(tcfrag, 80, W3, 512, b3, (float*)nullptr, xinfrag, 24);
  // gx = x_in @ gru_kernel + gru_bias
  k_small<0><<<dim3(24, 4), dim3(256), 0, stream>>>(xinfrag, 24, gru_kernel, 1536, gru_bias, gx, (unsigned short*)nullptr, 0);
  // h_new
  k_gru_act<<<dim3(128), dim3(256), 0, stream>>>(gx, out_h, hnfrag);
  // x1 = h_new @ fc1_W + fc1_b -> frags
  k_small<1><<<dim3(8, 4), dim3(256), 0, stream>>>(hnfrag, 16, fc1_W, 512, fc1_b, (float*)nullptr, x1frag, 16);
  // logits_out = x1 @ fc2_W + fc2_b
  k_fc2<<<dim3(500), dim3(256), 0, stream>>>(x1frag, fc2_W, fc2_b, out_logits);
}

// Round 3
// 205.476 us; speedup vs baseline: 1.2460x; 1.0930x over previous
//
#include <hip/hip_runtime.h>
#include <hip/hip_bf16.h>

#define B_N 256
#define L_Q 64
#define FEAT_N 2048
#define UNITS_N 512
#define EMB_N 256
#define VOCAB_N 32000

typedef __attribute__((ext_vector_type(8))) short bf16x8;
typedef __attribute__((ext_vector_type(4))) float f32x4;

__device__ __forceinline__ unsigned short f2bf(float x) {
  union { float f; unsigned int u; } c; c.f = x;
  unsigned int u = c.u + 0x7FFFu + ((c.u >> 16) & 1u);
  return (unsigned short)(u >> 16);
}

__device__ __forceinline__ float sigmoidf_(float x) { return 1.0f / (1.0f + __expf(-x)); }

// A-fragment layout for mfma_f32_16x16x32_bf16 (KS = K/32):
//   ushort index = ((rt*KS + ks)*64 + (lq*16+lr))*8 + j ; row = rt*16+lr, k = ks*32+lq*8+j
__device__ __forceinline__ void store_frag4(unsigned short* base, int KS, int row, int k0,
                                            float a, float b, float c, float d) {
  int rt = row >> 4, lr = row & 15;
  int ks = k0 >> 5, lq = (k0 >> 3) & 3, j0 = k0 & 7;
  union { unsigned long long u; unsigned short s[4]; } p;
  p.s[0] = f2bf(a); p.s[1] = f2bf(b); p.s[2] = f2bf(c); p.s[3] = f2bf(d);
  *reinterpret_cast<unsigned long long*>(base + (((rt * KS + ks) * 64) + (lq * 16 + lr)) * 8 + j0) = p.u;
}

__device__ __forceinline__ void gload_lds16(const void* g, void* lds) {
  __builtin_amdgcn_global_load_lds(
      (const __attribute__((address_space(1))) unsigned int*)(uintptr_t)g,
      (__attribute__((address_space(3))) unsigned int*)(unsigned)(uintptr_t)lds,
      16, 0, 0);
}

// B-fragment weight layout: idx = (((nt*4+ct)*KS + ks)*64 + l)*8 + j
//   lane l holds W[k = ks*32+(l>>4)*8+j][n = nt*64 + ct*16 + (l&15)]
__device__ __forceinline__ void wfrag_one(const float* __restrict__ W, int N, int KS,
                                          unsigned short* __restrict__ dst, int tid, int gruMap) {
  int l = tid & 63;
  int ks = (tid >> 6) % KS;
  int cts = tid / (64 * KS);
  int ct = cts & 3, nt = cts >> 2;
  int nb = gruMap ? (nt < 8 ? nt * 64 : 1024 + (nt - 8) * 64) : nt * 64;
  int ncol = nb + ct * 16 + (l & 15);
  int k0 = ks * 32 + (l >> 4) * 8;
  union { bf16x8 v; unsigned short s[8]; } fr;
#pragma unroll
  for (int j = 0; j < 8; ++j) fr.s[j] = f2bf(W[(size_t)(k0 + j) * N + ncol]);
  *reinterpret_cast<bf16x8*>(dst + (size_t)tid * 8) = fr.v;
}

// ---- fused prep: W1 frags, hidden/emb frags, and all small-weight frag conversions
__global__ void k_prep_all(const float* __restrict__ W1, unsigned short* __restrict__ W1s,
                           const float* __restrict__ hidden,
                           const float* __restrict__ emb_table,
                           const int* __restrict__ tok,
                           unsigned short* __restrict__ hfrag,
                           unsigned short* __restrict__ xinfrag,
                           const float* __restrict__ W2, unsigned short* __restrict__ W2f,
                           const float* __restrict__ W3, unsigned short* __restrict__ W3f,
                           const float* __restrict__ gruK, unsigned short* __restrict__ gruf,
                           const float* __restrict__ fc1W, unsigned short* __restrict__ fc1f) {
  int bb = blockIdx.x;
  if (bb < 512) {
    int t = bb * 256 + threadIdx.x;            // W1: one 16B frag each
    int l = t & 63;
    int c = (t >> 6) & 31;
    int kt = t >> 11;
    int n = c * 16 + (l & 15);
    int k0 = kt * 32 + (l >> 4) * 8;
    union { bf16x8 v; unsigned short s[8]; } fr;
#pragma unroll
    for (int j = 0; j < 8; ++j) fr.s[j] = f2bf(W1[(size_t)(k0 + j) * UNITS_N + n]);
    *reinterpret_cast<bf16x8*>(W1s + (size_t)t * 8) = fr.v;
  } else if (bb < 704) {
    int t = (bb - 512) * 256 + threadIdx.x;
    if (t < 32768) {
      int b = t >> 7, k0 = (t & 127) * 4;
      const float* s = hidden + (size_t)b * UNITS_N + k0;
      store_frag4(hfrag, 16, b, k0, s[0], s[1], s[2], s[3]);
    } else if (t < 49152) {
      int t2 = t - 32768;
      int b = t2 >> 6, e0 = (t2 & 63) * 4;
      const float* s = emb_table + (size_t)tok[b] * EMB_N + e0;
      store_frag4(xinfrag, 24, b, 512 + e0, s[0], s[1], s[2], s[3]);
    }
  } else if (bb < 832) {
    wfrag_one(W2, 512, 16, W2f, (bb - 704) * 256 + threadIdx.x, 0);
  } else if (bb < 1472) {
    wfrag_one(W3, 512, 80, W3f, (bb - 832) * 256 + threadIdx.x, 0);
  } else if (bb < 1856) {
    wfrag_one(gruK, 1536, 24, gruf, (bb - 1472) * 256 + threadIdx.x, 1);
  } else {
    wfrag_one(fc1W, 512, 16, fc1f, (bb - 1856) * 256 + threadIdx.x, 0);
  }
}

// ---- split-K small GEMM: block tile 32 rows x 64 cols; 4 waves each own K/4.
// No barriers in the main loop; one LDS reduction at the end.
// MODE 0: f32 row-major out. MODE 1: bf16 A-frag out (KSo). MODE 2: fused GRU act.
template <int MODE>
__launch_bounds__(256)
__global__ void k_small2(const unsigned short* __restrict__ Afrag, int KS,
                         const unsigned short* __restrict__ Bfrag,
                         const float* __restrict__ bias,
                         float* __restrict__ outF, int N,
                         unsigned short* __restrict__ outFrag, int KSo) {
  constexpr int NCT = (MODE == 2) ? 8 : 4;
  __shared__ f32x4 red[4][2][NCT][64];
  int t = threadIdx.x, w = t >> 6, l = t & 63;
  int nt = blockIdx.x;       // n-tile (64 cols); MODE2: paired z-tile (hh = 8+nt)
  int mb = blockIdx.y;       // 32-row tile
  int KSq = KS >> 2;

  f32x4 acc[2][NCT];
#pragma unroll
  for (int rt = 0; rt < 2; ++rt)
#pragma unroll
    for (int ct = 0; ct < NCT; ++ct) acc[rt][ct] = (f32x4){0.f, 0.f, 0.f, 0.f};

  for (int s = 0; s < KSq; ++s) {
    int ks = w * KSq + s;
    bf16x8 af[2];
#pragma unroll
    for (int rt = 0; rt < 2; ++rt)
      af[rt] = *reinterpret_cast<const bf16x8*>(Afrag + (((size_t)(mb * 2 + rt) * KS + ks) * 64 + l) * 8);
#pragma unroll
    for (int ct = 0; ct < NCT; ++ct) {
      int tile = (MODE == 2) ? (ct < 4 ? nt : 8 + nt) : nt;
      int cts = ct & 3;
      bf16x8 bf = *reinterpret_cast<const bf16x8*>(Bfrag + (((size_t)(tile * 4 + cts) * KS + ks) * 64 + l) * 8);
#pragma unroll
      for (int rt = 0; rt < 2; ++rt)
        acc[rt][ct] = __builtin_amdgcn_mfma_f32_16x16x32_bf16(af[rt], bf, acc[rt][ct], 0, 0, 0);
    }
  }

#pragma unroll
  for (int rt = 0; rt < 2; ++rt)
#pragma unroll
    for (int ct = 0; ct < NCT; ++ct) red[w][rt][ct][l] = acc[rt][ct];
  __syncthreads();

#pragma unroll
  for (int si = 0; si < 2; ++si) {
    int s = t + si * 256;                    // 512 slots: (rt, ct<4, l)
    int l2 = s & 63, ct = (s >> 6) & 3, rt = s >> 8;
    f32x4 v = red[0][rt][ct][l2];
#pragma unroll
    for (int ww = 1; ww < 4; ++ww) v += red[ww][rt][ct][l2];
    int col = nt * 64 + ct * 16 + (l2 & 15);
    int row0 = mb * 32 + rt * 16 + (l2 >> 4) * 4;
    if (MODE == 2) {
      f32x4 vh = red[0][rt][ct + 4][l2];
#pragma unroll
      for (int ww = 1; ww < 4; ++ww) vh += red[ww][rt][ct + 4][l2];
      float bz = bias[col], bh = bias[1024 + col];
#pragma unroll
      for (int i = 0; i < 4; ++i) {
        float hv = (1.f - sigmoidf_(v[i] + bz)) * tanhf(vh[i] + bh);
        int row = row0 + i;
        outF[(size_t)row * UNITS_N + col] = hv;
        int k = col;
        outFrag[(((size_t)(row >> 4) * KSo + (k >> 5)) * 64 + (((k >> 3) & 3) * 16 + (row & 15))) * 8 + (k & 7)] = f2bf(hv);
      }
    } else {
      float bv = bias[col];
#pragma unroll
      for (int i = 0; i < 4; ++i) {
        float vv = v[i] + bv;
        int row = row0 + i;
        if (MODE == 0) {
          outF[(size_t)row * N + col] = vv;
        } else {
          int k = col;
          outFrag[(((size_t)(row >> 4) * KSo + (k >> 5)) * 64 + (((k >> 3) & 3) * 16 + (row & 15))) * 8 + (k & 7)] = f2bf(vv);
        }
      }
    }
  }
}

// ---- GEMM1 partial: M=16384, N=512 (2 halves), K=2048. BM=64, BN=256, BK=32.
// 512 blocks, 4 waves; small LDS (21 KB) -> 5-6 blocks/CU for drain overlap.
__launch_bounds__(256, 5)
__global__ void k_gemm1p(const float* __restrict__ features,
                         const unsigned short* __restrict__ W1s,
                         const float* __restrict__ hproj,
                         const float* __restrict__ b1,
                         const float* __restrict__ V,
                         float* __restrict__ partials) {
  __shared__ unsigned short Bb[16 * 64 * 8];   // 16 KB
  __shared__ unsigned short Ab[4 * 64 * 8];    //  4 KB
  __shared__ float wlog[4][64];

  int t = threadIdx.x, w = t >> 6, l = t & 63;
  int bid = blockIdx.x;
  int swz = (bid & 7) * 64 + (bid >> 3);   // bijective, 512 = 8*64
  int h = swz & 1;                          // N half
  int mb = swz >> 1;                        // batch index (64 rows)

  f32x4 acc[4][4];
#pragma unroll
  for (int rt = 0; rt < 4; ++rt)
#pragma unroll
    for (int ct = 0; ct < 4; ++ct) acc[rt][ct] = (f32x4){0.f, 0.f, 0.f, 0.f};

  // A staging: thread -> row r = t>>2, k-octet q = t&3 (8 consecutive floats)
  int r = t >> 2, q = t & 3;
  const float* Ap = features + (size_t)(mb * 64 + r) * FEAT_N + q * 8;
  unsigned short* aw = &Ab[(((r >> 4) * 4 + q) * 16 + (r & 15)) * 8];

  const char* W1c = (const char*)W1s;
  float4 ar0 = *reinterpret_cast<const float4*>(Ap);
  float4 ar1 = *reinterpret_cast<const float4*>(Ap + 4);

  for (int kt = 0; kt < 64; ++kt) {
    __syncthreads();
    // B: 16 chunks of 1KB via global_load_lds (4 per wave)
#pragma unroll
    for (int i = 0; i < 4; ++i)
      gload_lds16(W1c + (((size_t)(kt * 32 + h * 16 + w * 4 + i)) << 10) + (size_t)l * 16,
                  (char*)Bb + ((w * 4 + i) << 10));
    // A: convert regs -> frag
    {
      union { bf16x8 v; unsigned short s_[8]; } p;
      p.s_[0] = f2bf(ar0.x); p.s_[1] = f2bf(ar0.y); p.s_[2] = f2bf(ar0.z); p.s_[3] = f2bf(ar0.w);
      p.s_[4] = f2bf(ar1.x); p.s_[5] = f2bf(ar1.y); p.s_[6] = f2bf(ar1.z); p.s_[7] = f2bf(ar1.w);
      *reinterpret_cast<bf16x8*>(aw) = p.v;
    }
    if (kt + 1 < 64) {
      const float* p = Ap + (kt + 1) * 32;
      ar0 = *reinterpret_cast<const float4*>(p);
      ar1 = *reinterpret_cast<const float4*>(p + 4);
    }
    __syncthreads();
    bf16x8 af[4];
#pragma unroll
    for (int rt = 0; rt < 4; ++rt)
      af[rt] = *reinterpret_cast<const bf16x8*>(&Ab[(rt * 64 + l) * 8]);
#pragma unroll
    for (int ct = 0; ct < 4; ++ct) {
      bf16x8 bfr = *reinterpret_cast<const bf16x8*>(&Bb[((w * 4 + ct) * 64 + l) * 8]);
#pragma unroll
      for (int rt = 0; rt < 4; ++rt)
        acc[rt][ct] = __builtin_amdgcn_mfma_f32_16x16x32_bf16(af[rt], bfr, acc[rt][ct], 0, 0, 0);
    }
  }

  // epilogue: partial logits over this half's 256 cols
  float rowpart[16];
#pragma unroll
  for (int i = 0; i < 16; ++i) rowpart[i] = 0.f;
#pragma unroll
  for (int ct = 0; ct < 4; ++ct) {
    int col = h * 256 + w * 64 + ct * 16 + (l & 15);
    float hb = hproj[(size_t)mb * UNITS_N + col] + b1[col];
    float vv = V[col];
#pragma unroll
    for (int rt = 0; rt < 4; ++rt)
#pragma unroll
      for (int i = 0; i < 4; ++i)
        rowpart[rt * 4 + i] += tanhf(acc[rt][ct][i] + hb) * vv;
  }
#pragma unroll
  for (int m = 1; m <= 8; m <<= 1)
#pragma unroll
    for (int i = 0; i < 16; ++i) rowpart[i] += __shfl_xor(rowpart[i], m, 64);
  if ((l & 15) == 0) {
    int g = l >> 4;
#pragma unroll
    for (int rt = 0; rt < 4; ++rt)
#pragma unroll
      for (int i = 0; i < 4; ++i)
        wlog[w][rt * 16 + g * 4 + i] = rowpart[rt * 4 + i];
  }
  __syncthreads();
  if (t < 64) {
    float x = wlog[0][t] + wlog[1][t] + wlog[2][t] + wlog[3][t];
    partials[h * 16384 + mb * 64 + t] = x;
  }
}

// ---- softmax (from 2 partials) + context + tanh-concat frags
__global__ void k_context(const float* __restrict__ features,
                          const float* __restrict__ partials,
                          const float* __restrict__ hidden,
                          unsigned short* __restrict__ tcfrag,
                          float* __restrict__ attn_out) {
  __shared__ float aL[64];
  int b = blockIdx.x, t = threadIdx.x;
  if (t < 64) {
    float x = partials[b * 64 + t] + partials[16384 + b * 64 + t];
    float mx = x;
#pragma unroll
    for (int m = 1; m < 64; m <<= 1) mx = fmaxf(mx, __shfl_xor(mx, m, 64));
    float e = __expf(x - mx);
    float s = e;
#pragma unroll
    for (int m = 1; m < 64; m <<= 1) s += __shfl_xor(s, m, 64);
    float a = e / s;
    aL[t] = a;
    attn_out[(size_t)b * 64 + t] = a;
  }
  __syncthreads();
  const float* F = features + (size_t)b * 64 * FEAT_N + t * 4;
  float a0 = 0.f, a1 = 0.f, a2 = 0.f, a3 = 0.f;
#pragma unroll 4
  for (int lr = 0; lr < 64; ++lr) {
    float4 f = *reinterpret_cast<const float4*>(F + (size_t)lr * FEAT_N);
    float av = aL[lr];
    a0 += av * f.x; a1 += av * f.y; a2 += av * f.z; a3 += av * f.w;
  }
  store_frag4(tcfrag, 80, b, t * 4, tanhf(a0), tanhf(a1), tanhf(a2), tanhf(a3));
  if (t < 128) {
    const float* H = hidden + (size_t)b * UNITS_N + t * 4;
    store_frag4(tcfrag, 80, b, 2048 + t * 4, tanhf(H[0]), tanhf(H[1]), tanhf(H[2]), tanhf(H[3]));
  }
}

// ---- fc2: out(256x32000) = x1 @ fc2_W + fc2_b
__launch_bounds__(256)
__global__ void k_fc2(const unsigned short* __restrict__ x1frag,
                      const float* __restrict__ W, const float* __restrict__ bias,
                      float* __restrict__ out) {
  __shared__ unsigned short Bb[4 * 64 * 8];
  int t = threadIdx.x, w = t >> 6, l = t & 63;
  int n0 = blockIdx.x * 64;
  f32x4 acc[4][4];
#pragma unroll
  for (int r = 0; r < 4; ++r)
#pragma unroll
    for (int c = 0; c < 4; ++c) acc[r][c] = (f32x4){0.f, 0.f, 0.f, 0.f};

  int sn = t & 63, kc = t >> 6;
  unsigned short* wdst = &Bb[(((sn >> 4) * 64) + ((sn & 15) | (kc << 4))) * 8];
  const float* Wp = W + n0 + sn;
  float wreg[8];
#pragma unroll
  for (int j = 0; j < 8; ++j) wreg[j] = Wp[(size_t)(kc * 8 + j) * VOCAB_N];

  for (int kt = 0; kt < 16; ++kt) {
    __syncthreads();
    {
      union { bf16x8 v; unsigned short s[8]; } p;
#pragma unroll
      for (int j = 0; j < 8; ++j) p.s[j] = f2bf(wreg[j]);
      *reinterpret_cast<bf16x8*>(wdst) = p.v;
    }
    __syncthreads();
    if (kt < 15) {
#pragma unroll
      for (int j = 0; j < 8; ++j) wreg[j] = Wp[(size_t)((kt + 1) * 32 + kc * 8 + j) * VOCAB_N];
    }
    bf16x8 bf[4];
#pragma unroll
    for (int c = 0; c < 4; ++c) bf[c] = *reinterpret_cast<const bf16x8*>(&Bb[((c * 64) + l) * 8]);
#pragma unroll
    for (int rti = 0; rti < 4; ++rti) {
      bf16x8 af = *reinterpret_cast<const bf16x8*>(x1frag + ((size_t)((w * 4 + rti) * 16 + kt) * 64 + l) * 8);
#pragma unroll
      for (int c = 0; c < 4; ++c)
        acc[rti][c] = __builtin_amdgcn_mfma_f32_16x16x32_bf16(af, bf[c], acc[rti][c], 0, 0, 0);
    }
  }
#pragma unroll
  for (int c = 0; c < 4; ++c) {
    int col = n0 + c * 16 + (l & 15);
    float bv = bias[col];
#pragma unroll
    for (int rti = 0; rti < 4; ++rti)
#pragma unroll
      for (int i = 0; i < 4; ++i) {
        int row = w * 64 + rti * 16 + (l >> 4) * 4 + i;
        out[(size_t)row * VOCAB_N + col] = acc[rti][c][i] + bv;
      }
  }
}

extern "C" void kernel_launch(void* const* d_in, const int* in_sizes, int n_in,
                              void* d_out, int out_size, void* d_ws, size_t ws_size,
                              hipStream_t stream) {
  const int*   tok        = (const int*)d_in[0];
  const float* features   = (const float*)d_in[1];
  const float* hidden     = (const float*)d_in[2];
  const float* W1         = (const float*)d_in[3];
  const float* b1         = (const float*)d_in[4];
  const float* W2         = (const float*)d_in[5];
  const float* b2         = (const float*)d_in[6];
  const float* V          = (const float*)d_in[7];
  // d_in[8] = bV: cancels in softmax
  const float* W3         = (const float*)d_in[9];
  const float* b3         = (const float*)d_in[10];
  const float* emb_table  = (const float*)d_in[11];
  const float* gru_kernel = (const float*)d_in[12];
  // d_in[13] = gru_rec: unused (h0 == 0); r-gate columns of gru_kernel also dead
  const float* gru_bias   = (const float*)d_in[14];
  const float* fc1_W      = (const float*)d_in[15];
  const float* fc1_b      = (const float*)d_in[16];
  const float* fc2_W      = (const float*)d_in[17];
  const float* fc2_b      = (const float*)d_in[18];

  float* out_logits = (float*)d_out;
  float* out_h      = out_logits + (size_t)B_N * VOCAB_N;
  float* out_attn   = out_h + (size_t)B_N * UNITS_N;

  char* ws = (char*)d_ws;
  unsigned short* W1s     = (unsigned short*)(ws);               // 2,097,152
  float*          hproj   = (float*)(ws + 2097152);              //   524,288
  unsigned short* hfrag   = (unsigned short*)(ws + 2621440);     //   262,144
  unsigned short* tcfrag  = (unsigned short*)(ws + 2883584);     // 1,310,720
  unsigned short* xinfrag = (unsigned short*)(ws + 4194304);     //   393,216
  unsigned short* hnfrag  = (unsigned short*)(ws + 4587520);     //   262,144
  unsigned short* x1frag  = (unsigned short*)(ws + 4849664);     //   262,144
  float*          partials= (float*)(ws + 5111808);              //   131,072
  unsigned short* W2f     = (unsigned short*)(ws + 5242880);     //   524,288
  unsigned short* W3f     = (unsigned short*)(ws + 5767168);     // 2,621,440
  unsigned short* gruf    = (unsigned short*)(ws + 8388608);     // 1,572,864
  unsigned short* fc1f    = (unsigned short*)(ws + 9961472);     //   524,288

  k_prep_all<<<dim3(1984), dim3(256), 0, stream>>>(W1, W1s, hidden, emb_table, tok,
                                                   hfrag, xinfrag, W2, W2f, W3, W3f,
                                                   gru_kernel, gruf, fc1_W, fc1f);
  // hproj = hidden @ W2 + b2
  k_small2<0><<<dim3(8, 8), dim3(256), 0, stream>>>(hfrag, 16, W2f, b2, hproj, 512,
                                                    (unsigned short*)nullptr, 0);
  // partial logits
  k_gemm1p<<<dim3(512), dim3(256), 0, stream>>>(features, W1s, hproj, b1, V, partials);
  // softmax + context + tanh-concat frags (writes attn output)
  k_context<<<dim3(256), dim3(512), 0, stream>>>(features, partials, hidden, tcfrag, out_attn);
  // cvh = tc @ W3 + b3 -> xin frags (k 0..511)
  k_small2<1><<<dim3(8, 8), dim3(256), 0, stream>>>(tcfrag, 80, W3f, b3, (float*)nullptr, 0,
                                                    xinfrag, 24);
  // gru: z/hh GEMM fused with activation -> out_h + hn frags
  k_small2<2><<<dim3(8, 8), dim3(256), 0, stream>>>(xinfrag, 24, gruf, gru_bias, out_h, 512,
                                                    hnfrag, 16);
  // x1 = h_new @ fc1_W + fc1_b -> frags
  k_small2<1><<<dim3(8, 8), dim3(256), 0, stream>>>(hnfrag, 16, fc1f, fc1_b, (float*)nullptr, 0,
                                                    x1frag, 16);
  // logits_out = x1 @ fc2_W + fc2_b
  k_fc2<<<dim3(500), dim3(256), 0, stream>>>(x1frag, fc2_W, fc2_b, out_logits);
}

// Round 4
// 175.838 us; speedup vs baseline: 1.4560x; 1.1686x over previous
//
#include <hip/hip_runtime.h>
#include <hip/hip_bf16.h>

#define B_N 256
#define L_Q 64
#define FEAT_N 2048
#define UNITS_N 512
#define EMB_N 256
#define VOCAB_N 32000

typedef __attribute__((ext_vector_type(8))) short bf16x8;
typedef __attribute__((ext_vector_type(4))) float f32x4;

__device__ __forceinline__ unsigned short f2bf(float x) {
  union { float f; unsigned int u; } c; c.f = x;
  unsigned int u = c.u + 0x7FFFu + ((c.u >> 16) & 1u);
  return (unsigned short)(u >> 16);
}

__device__ __forceinline__ float sigmoidf_(float x) { return 1.0f / (1.0f + __expf(-x)); }

// A-fragment layout for mfma_f32_16x16x32_bf16 (KS = K/32):
//   ushort index = ((rt*KS + ks)*64 + (lq*16+lr))*8 + j ; row = rt*16+lr, k = ks*32+lq*8+j
__device__ __forceinline__ void store_frag4(unsigned short* base, int KS, int row, int k0,
                                            float a, float b, float c, float d) {
  int rt = row >> 4, lr = row & 15;
  int ks = k0 >> 5, lq = (k0 >> 3) & 3, j0 = k0 & 7;
  union { unsigned long long u; unsigned short s[4]; } p;
  p.s[0] = f2bf(a); p.s[1] = f2bf(b); p.s[2] = f2bf(c); p.s[3] = f2bf(d);
  *reinterpret_cast<unsigned long long*>(base + (((rt * KS + ks) * 64) + (lq * 16 + lr)) * 8 + j0) = p.u;
}

// B-fragment weight layout: idx = (((nt*4+ct)*KS + ks)*64 + l)*8 + j
__device__ __forceinline__ void wfrag_one(const float* __restrict__ W, int N, int KS,
                                          unsigned short* __restrict__ dst, int tid, int gruMap) {
  int l = tid & 63;
  int ks = (tid >> 6) % KS;
  int cts = tid / (64 * KS);
  int ct = cts & 3, nt = cts >> 2;
  int nb = gruMap ? (nt < 8 ? nt * 64 : 1024 + (nt - 8) * 64) : nt * 64;
  int ncol = nb + ct * 16 + (l & 15);
  int k0 = ks * 32 + (l >> 4) * 8;
  union { bf16x8 v; unsigned short s[8]; } fr;
#pragma unroll
  for (int j = 0; j < 8; ++j) fr.s[j] = f2bf(W[(size_t)(k0 + j) * N + ncol]);
  *reinterpret_cast<bf16x8*>(dst + (size_t)tid * 8) = fr.v;
}

// ---- fused prep: W1 frags, hidden/emb frags, and small-weight frag conversions
__global__ void k_prep_all(const float* __restrict__ W1, unsigned short* __restrict__ W1s,
                           const float* __restrict__ hidden,
                           const float* __restrict__ emb_table,
                           const int* __restrict__ tok,
                           unsigned short* __restrict__ hfrag,
                           unsigned short* __restrict__ xinfrag,
                           const float* __restrict__ W2, unsigned short* __restrict__ W2f,
                           const float* __restrict__ W3, unsigned short* __restrict__ W3f,
                           const float* __restrict__ gruK, unsigned short* __restrict__ gruf,
                           const float* __restrict__ fc1W, unsigned short* __restrict__ fc1f) {
  int bb = blockIdx.x;
  if (bb < 512) {
    int t = bb * 256 + threadIdx.x;            // W1: one 16B frag each
    int l = t & 63;
    int c = (t >> 6) & 31;
    int kt = t >> 11;
    int n = c * 16 + (l & 15);
    int k0 = kt * 32 + (l >> 4) * 8;
    union { bf16x8 v; unsigned short s[8]; } fr;
#pragma unroll
    for (int j = 0; j < 8; ++j) fr.s[j] = f2bf(W1[(size_t)(k0 + j) * UNITS_N + n]);
    *reinterpret_cast<bf16x8*>(W1s + (size_t)t * 8) = fr.v;
  } else if (bb < 704) {
    int t = (bb - 512) * 256 + threadIdx.x;
    if (t < 32768) {
      int b = t >> 7, k0 = (t & 127) * 4;
      const float* s = hidden + (size_t)b * UNITS_N + k0;
      store_frag4(hfrag, 16, b, k0, s[0], s[1], s[2], s[3]);
    } else if (t < 49152) {
      int t2 = t - 32768;
      int b = t2 >> 6, e0 = (t2 & 63) * 4;
      const float* s = emb_table + (size_t)tok[b] * EMB_N + e0;
      store_frag4(xinfrag, 24, b, 512 + e0, s[0], s[1], s[2], s[3]);
    }
  } else if (bb < 832) {
    wfrag_one(W2, 512, 16, W2f, (bb - 704) * 256 + threadIdx.x, 0);
  } else if (bb < 1472) {
    wfrag_one(W3, 512, 80, W3f, (bb - 832) * 256 + threadIdx.x, 0);
  } else if (bb < 1856) {
    wfrag_one(gruK, 1536, 24, gruf, (bb - 1472) * 256 + threadIdx.x, 1);
  } else {
    wfrag_one(fc1W, 512, 16, fc1f, (bb - 1856) * 256 + threadIdx.x, 0);
  }
}

// ---- split-K small GEMM (round-3 winner, unchanged)
template <int MODE>
__launch_bounds__(256)
__global__ void k_small2(const unsigned short* __restrict__ Afrag, int KS,
                         const unsigned short* __restrict__ Bfrag,
                         const float* __restrict__ bias,
                         float* __restrict__ outF, int N,
                         unsigned short* __restrict__ outFrag, int KSo) {
  constexpr int NCT = (MODE == 2) ? 8 : 4;
  __shared__ f32x4 red[4][2][NCT][64];
  int t = threadIdx.x, w = t >> 6, l = t & 63;
  int nt = blockIdx.x;
  int mb = blockIdx.y;
  int KSq = KS >> 2;

  f32x4 acc[2][NCT];
#pragma unroll
  for (int rt = 0; rt < 2; ++rt)
#pragma unroll
    for (int ct = 0; ct < NCT; ++ct) acc[rt][ct] = (f32x4){0.f, 0.f, 0.f, 0.f};

  for (int s = 0; s < KSq; ++s) {
    int ks = w * KSq + s;
    bf16x8 af[2];
#pragma unroll
    for (int rt = 0; rt < 2; ++rt)
      af[rt] = *reinterpret_cast<const bf16x8*>(Afrag + (((size_t)(mb * 2 + rt) * KS + ks) * 64 + l) * 8);
#pragma unroll
    for (int ct = 0; ct < NCT; ++ct) {
      int tile = (MODE == 2) ? (ct < 4 ? nt : 8 + nt) : nt;
      int cts = ct & 3;
      bf16x8 bf = *reinterpret_cast<const bf16x8*>(Bfrag + (((size_t)(tile * 4 + cts) * KS + ks) * 64 + l) * 8);
#pragma unroll
      for (int rt = 0; rt < 2; ++rt)
        acc[rt][ct] = __builtin_amdgcn_mfma_f32_16x16x32_bf16(af[rt], bf, acc[rt][ct], 0, 0, 0);
    }
  }

#pragma unroll
  for (int rt = 0; rt < 2; ++rt)
#pragma unroll
    for (int ct = 0; ct < NCT; ++ct) red[w][rt][ct][l] = acc[rt][ct];
  __syncthreads();

#pragma unroll
  for (int si = 0; si < 2; ++si) {
    int s = t + si * 256;
    int l2 = s & 63, ct = (s >> 6) & 3, rt = s >> 8;
    f32x4 v = red[0][rt][ct][l2];
#pragma unroll
    for (int ww = 1; ww < 4; ++ww) v += red[ww][rt][ct][l2];
    int col = nt * 64 + ct * 16 + (l2 & 15);
    int row0 = mb * 32 + rt * 16 + (l2 >> 4) * 4;
    if (MODE == 2) {
      f32x4 vh = red[0][rt][ct + 4][l2];
#pragma unroll
      for (int ww = 1; ww < 4; ++ww) vh += red[ww][rt][ct + 4][l2];
      float bz = bias[col], bh = bias[1024 + col];
#pragma unroll
      for (int i = 0; i < 4; ++i) {
        float hv = (1.f - sigmoidf_(v[i] + bz)) * tanhf(vh[i] + bh);
        int row = row0 + i;
        outF[(size_t)row * UNITS_N + col] = hv;
        int k = col;
        outFrag[(((size_t)(row >> 4) * KSo + (k >> 5)) * 64 + (((k >> 3) & 3) * 16 + (row & 15))) * 8 + (k & 7)] = f2bf(hv);
      }
    } else {
      float bv = bias[col];
#pragma unroll
      for (int i = 0; i < 4; ++i) {
        float vv = v[i] + bv;
        int row = row0 + i;
        if (MODE == 0) {
          outF[(size_t)row * N + col] = vv;
        } else {
          int k = col;
          outFrag[(((size_t)(row >> 4) * KSo + (k >> 5)) * 64 + (((k >> 3) & 3) * 16 + (row & 15))) * 8 + (k & 7)] = f2bf(vv);
        }
      }
    }
  }
}

// ---- GEMM1 fused: one block per batch. 8 waves, each wave 32 rows x 128 cols, FULL K.
// No barriers in the K loop; B frags read straight from L2-resident W1s; A frags
// converted in-register from features. Epilogue: tanh*V partial -> LDS reduce ->
// in-block softmax -> attn out -> fused context + tanh-concat frags.
__launch_bounds__(512, 2)
__global__ void k_gemm1f(const float* __restrict__ features,
                         const unsigned short* __restrict__ W1s,
                         const float* __restrict__ hproj,
                         const float* __restrict__ b1,
                         const float* __restrict__ V,
                         const float* __restrict__ hidden,
                         float* __restrict__ attn_out,
                         unsigned short* __restrict__ tcfrag) {
  __shared__ float wlog[8][32];
  __shared__ float aL[64];

  int b = blockIdx.x;
  int t = threadIdx.x, w = t >> 6, l = t & 63;
  int wr = w >> 2, wc = w & 3;

  f32x4 acc[2][8];
#pragma unroll
  for (int rt = 0; rt < 2; ++rt)
#pragma unroll
    for (int ct = 0; ct < 8; ++ct) acc[rt][ct] = (f32x4){0.f, 0.f, 0.f, 0.f};

  const float* Arow = features + ((size_t)(b * 64 + wr * 32 + (l & 15))) * FEAT_N + ((l >> 4) * 8);
  const unsigned short* Bcol = W1s + ((size_t)(wc * 8) * 64 + l) * 8;

  for (int kt = 0; kt < 64; ++kt) {
    bf16x8 af[2];
#pragma unroll
    for (int rt = 0; rt < 2; ++rt) {
      const float* p = Arow + (size_t)rt * 16 * FEAT_N + kt * 32;
      float4 x0 = *reinterpret_cast<const float4*>(p);
      float4 x1 = *reinterpret_cast<const float4*>(p + 4);
      union { bf16x8 v; unsigned short s[8]; } u;
      u.s[0] = f2bf(x0.x); u.s[1] = f2bf(x0.y); u.s[2] = f2bf(x0.z); u.s[3] = f2bf(x0.w);
      u.s[4] = f2bf(x1.x); u.s[5] = f2bf(x1.y); u.s[6] = f2bf(x1.z); u.s[7] = f2bf(x1.w);
      af[rt] = u.v;
    }
#pragma unroll
    for (int ct = 0; ct < 8; ++ct) {
      bf16x8 bv = *reinterpret_cast<const bf16x8*>(Bcol + ((size_t)(kt * 32 + ct) * 64) * 8);
      acc[0][ct] = __builtin_amdgcn_mfma_f32_16x16x32_bf16(af[0], bv, acc[0][ct], 0, 0, 0);
      acc[1][ct] = __builtin_amdgcn_mfma_f32_16x16x32_bf16(af[1], bv, acc[1][ct], 0, 0, 0);
    }
  }

  // partial logits over this wave's 128 cols
  float rowpart[8];
#pragma unroll
  for (int i = 0; i < 8; ++i) rowpart[i] = 0.f;
#pragma unroll
  for (int ct = 0; ct < 8; ++ct) {
    int col = (wc * 8 + ct) * 16 + (l & 15);
    float hb = hproj[(size_t)b * UNITS_N + col] + b1[col];
    float vv = V[col];
#pragma unroll
    for (int rt = 0; rt < 2; ++rt)
#pragma unroll
      for (int i = 0; i < 4; ++i)
        rowpart[rt * 4 + i] += tanhf(acc[rt][ct][i] + hb) * vv;
  }
#pragma unroll
  for (int m = 1; m <= 8; m <<= 1)
#pragma unroll
    for (int i = 0; i < 8; ++i) rowpart[i] += __shfl_xor(rowpart[i], m, 64);
  if ((l & 15) == 0) {
    int g = l >> 4;
#pragma unroll
    for (int rt = 0; rt < 2; ++rt)
#pragma unroll
      for (int i = 0; i < 4; ++i)
        wlog[w][rt * 16 + g * 4 + i] = rowpart[rt * 4 + i];
  }
  __syncthreads();
  if (t < 64) {
    int wr2 = t >> 5, rl = t & 31;
    float x = wlog[wr2 * 4 + 0][rl] + wlog[wr2 * 4 + 1][rl] +
              wlog[wr2 * 4 + 2][rl] + wlog[wr2 * 4 + 3][rl];
    float mx = x;
#pragma unroll
    for (int m = 1; m < 64; m <<= 1) mx = fmaxf(mx, __shfl_xor(mx, m, 64));
    float e = __expf(x - mx);
    float s = e;
#pragma unroll
    for (int m = 1; m < 64; m <<= 1) s += __shfl_xor(s, m, 64);
    float a = e / s;
    aL[t] = a;
    attn_out[(size_t)b * 64 + t] = a;
  }
  __syncthreads();

  // fused context: 512 threads x 4 cols
  {
    const float* F = features + (size_t)b * 64 * FEAT_N + t * 4;
    float a0 = 0.f, a1 = 0.f, a2 = 0.f, a3 = 0.f;
#pragma unroll 4
    for (int lr = 0; lr < 64; ++lr) {
      float4 f = *reinterpret_cast<const float4*>(F + (size_t)lr * FEAT_N);
      float av = aL[lr];
      a0 += av * f.x; a1 += av * f.y; a2 += av * f.z; a3 += av * f.w;
    }
    store_frag4(tcfrag, 80, b, t * 4, tanhf(a0), tanhf(a1), tanhf(a2), tanhf(a3));
  }
  if (t < 128) {
    const float* H = hidden + (size_t)b * UNITS_N + t * 4;
    store_frag4(tcfrag, 80, b, 2048 + t * 4, tanhf(H[0]), tanhf(H[1]), tanhf(H[2]), tanhf(H[3]));
  }
}

// ---- fc2: out = x1 @ fc2_W + fc2_b. grid (500, 2): 128 rows x 64 cols per block.
__launch_bounds__(256)
__global__ void k_fc2(const unsigned short* __restrict__ x1frag,
                      const float* __restrict__ W, const float* __restrict__ bias,
                      float* __restrict__ out) {
  __shared__ unsigned short Bb[4 * 64 * 8];
  int t = threadIdx.x, w = t >> 6, l = t & 63;
  int n0 = blockIdx.x * 64;
  int mh = blockIdx.y;
  f32x4 acc[2][4];
#pragma unroll
  for (int r = 0; r < 2; ++r)
#pragma unroll
    for (int c = 0; c < 4; ++c) acc[r][c] = (f32x4){0.f, 0.f, 0.f, 0.f};

  int sn = t & 63, kc = t >> 6;
  unsigned short* wdst = &Bb[(((sn >> 4) * 64) + ((sn & 15) | (kc << 4))) * 8];
  const float* Wp = W + n0 + sn;
  float wreg[8];
#pragma unroll
  for (int j = 0; j < 8; ++j) wreg[j] = Wp[(size_t)(kc * 8 + j) * VOCAB_N];

  for (int kt = 0; kt < 16; ++kt) {
    __syncthreads();
    {
      union { bf16x8 v; unsigned short s[8]; } p;
#pragma unroll
      for (int j = 0; j < 8; ++j) p.s[j] = f2bf(wreg[j]);
      *reinterpret_cast<bf16x8*>(wdst) = p.v;
    }
    __syncthreads();
    if (kt < 15) {
#pragma unroll
      for (int j = 0; j < 8; ++j) wreg[j] = Wp[(size_t)((kt + 1) * 32 + kc * 8 + j) * VOCAB_N];
    }
    bf16x8 bf[4];
#pragma unroll
    for (int c = 0; c < 4; ++c) bf[c] = *reinterpret_cast<const bf16x8*>(&Bb[((c * 64) + l) * 8]);
#pragma unroll
    for (int rti = 0; rti < 2; ++rti) {
      int rtg = mh * 8 + w * 2 + rti;
      bf16x8 af = *reinterpret_cast<const bf16x8*>(x1frag + ((size_t)(rtg * 16 + kt) * 64 + l) * 8);
#pragma unroll
      for (int c = 0; c < 4; ++c)
        acc[rti][c] = __builtin_amdgcn_mfma_f32_16x16x32_bf16(af, bf[c], acc[rti][c], 0, 0, 0);
    }
  }
#pragma unroll
  for (int c = 0; c < 4; ++c) {
    int col = n0 + c * 16 + (l & 15);
    float bv = bias[col];
#pragma unroll
    for (int rti = 0; rti < 2; ++rti)
#pragma unroll
      for (int i = 0; i < 4; ++i) {
        int row = mh * 128 + w * 32 + rti * 16 + (l >> 4) * 4 + i;
        out[(size_t)row * VOCAB_N + col] = acc[rti][c][i] + bv;
      }
  }
}

extern "C" void kernel_launch(void* const* d_in, const int* in_sizes, int n_in,
                              void* d_out, int out_size, void* d_ws, size_t ws_size,
                              hipStream_t stream) {
  const int*   tok        = (const int*)d_in[0];
  const float* features   = (const float*)d_in[1];
  const float* hidden     = (const float*)d_in[2];
  const float* W1         = (const float*)d_in[3];
  const float* b1         = (const float*)d_in[4];
  const float* W2         = (const float*)d_in[5];
  const float* b2         = (const float*)d_in[6];
  const float* V          = (const float*)d_in[7];
  // d_in[8] = bV: cancels in softmax
  const float* W3         = (const float*)d_in[9];
  const float* b3         = (const float*)d_in[10];
  const float* emb_table  = (const float*)d_in[11];
  const float* gru_kernel = (const float*)d_in[12];
  // d_in[13] = gru_rec: unused (h0 == 0); r-gate columns of gru_kernel also dead
  const float* gru_bias   = (const float*)d_in[14];
  const float* fc1_W      = (const float*)d_in[15];
  const float* fc1_b      = (const float*)d_in[16];
  const float* fc2_W      = (const float*)d_in[17];
  const float* fc2_b      = (const float*)d_in[18];

  float* out_logits = (float*)d_out;
  float* out_h      = out_logits + (size_t)B_N * VOCAB_N;
  float* out_attn   = out_h + (size_t)B_N * UNITS_N;

  char* ws = (char*)d_ws;
  unsigned short* W1s     = (unsigned short*)(ws);               // 2,097,152
  float*          hproj   = (float*)(ws + 2097152);              //   524,288
  unsigned short* hfrag   = (unsigned short*)(ws + 2621440);     //   262,144
  unsigned short* tcfrag  = (unsigned short*)(ws + 2883584);     // 1,310,720
  unsigned short* xinfrag = (unsigned short*)(ws + 4194304);     //   393,216
  unsigned short* hnfrag  = (unsigned short*)(ws + 4587520);     //   262,144
  unsigned short* x1frag  = (unsigned short*)(ws + 4849664);     //   262,144
  unsigned short* W2f     = (unsigned short*)(ws + 5242880);     //   524,288
  unsigned short* W3f     = (unsigned short*)(ws + 5767168);     // 2,621,440
  unsigned short* gruf    = (unsigned short*)(ws + 8388608);     // 1,572,864
  unsigned short* fc1f    = (unsigned short*)(ws + 9961472);     //   524,288

  k_prep_all<<<dim3(1984), dim3(256), 0, stream>>>(W1, W1s, hidden, emb_table, tok,
                                                   hfrag, xinfrag, W2, W2f, W3, W3f,
                                                   gru_kernel, gruf, fc1_W, fc1f);
  // hproj = hidden @ W2 + b2
  k_small2<0><<<dim3(8, 8), dim3(256), 0, stream>>>(hfrag, 16, W2f, b2, hproj, 512,
                                                    (unsigned short*)nullptr, 0);
  // fused GEMM1 + softmax + attn + context + tanh-concat frags
  k_gemm1f<<<dim3(256), dim3(512), 0, stream>>>(features, W1s, hproj, b1, V, hidden,
                                                out_attn, tcfrag);
  // cvh = tc @ W3 + b3 -> xin frags (k 0..511)
  k_small2<1><<<dim3(8, 8), dim3(256), 0, stream>>>(tcfrag, 80, W3f, b3, (float*)nullptr, 0,
                                                    xinfrag, 24);
  // gru: z/hh GEMM fused with activation -> out_h + hn frags
  k_small2<2><<<dim3(8, 8), dim3(256), 0, stream>>>(xinfrag, 24, gruf, gru_bias, out_h, 512,
                                                    hnfrag, 16);
  // x1 = h_new @ fc1_W + fc1_b -> frags
  k_small2<1><<<dim3(8, 8), dim3(256), 0, stream>>>(hnfrag, 16, fc1f, fc1_b, (float*)nullptr, 0,
                                                    x1frag, 16);
  // logits_out = x1 @ fc2_W + fc2_b
  k_fc2<<<dim3(500, 2), dim3(256), 0, stream>>>(x1frag, fc2_W, fc2_b, out_logits);
}